// Round 5
// baseline (64364.508 us; speedup 1.0000x reference)
//
#include <hip/hip_runtime.h>
#include <hip/hip_bf16.h>

typedef unsigned short u16;
typedef unsigned int u32;

#define KB_T 0.025851f
#define HS (1024 * 512)

// d_out (FLOAT32): preds.T [1024][32] | E [1024] | gens.T [1024][32] | bps.T [1024][32]
#define OFF_E    32768
#define OFF_GENS 33792
#define OFF_BPS  66560

// ---- workspace layout (byte offsets)
#define WS_X0    0u         // [1024][257] u16 (col0 = s, cols1..256 = latent)
#define WS_PRD   528384u    // [1024] f32
#define WS_EE    532480u    // [1024] f32
#define WS_RATE  536576u    // [1024] f32
#define WS_SP    540672u    // [1024] f32
#define WS_H0    544768u    // 2x[1024][512] u16 ping-pong
#define WS_H1    2641920u   // 2x[1024][512] u16
#define WS_C0    4739072u   // [1024][512] u16
#define WS_C1    5787648u   // [1024][512] u16
#define WS_F1    6836224u   // [1024][256] u16
#define WS_F2    7360512u   // [1024][256] u16
#define WS_FLAG  7884800u   // int: 1 = inputs fp32, 0 = inputs bf16

__device__ __forceinline__ float b2f(u16 u) { u32 x = ((u32)u) << 16; float f; __builtin_memcpy(&f, &x, 4); return f; }
__device__ __forceinline__ u16 f2b(float f) { __hip_bfloat16 h = __float2bfloat16(f); u16 u; __builtin_memcpy(&u, &h, 2); return u; }
__device__ __forceinline__ float sigf(float x) { return 1.f / (1.f + __expf(-x)); }
__device__ __forceinline__ float tanh_(float x) { return 1.f - 2.f / (__expf(2.f * x) + 1.f); }
__device__ __forceinline__ float gelu_(float x) { return 0.5f * x * (1.f + tanh_(0.7978845608f * (x + 0.044715f * x * x * x))); }

// adaptive external-input load: f32 flag chooses fp32 or bf16 element read
__device__ __forceinline__ float gld(const void* p, int i, int f32) {
    return f32 ? ((const float*)p)[i] : b2f(((const u16*)p)[i]);
}

// ---------------------------------------------------------------------------
// dtype probe: voltage values are in [0,3). As fp32 u32s they decode < 100.
// As packed bf16 pairs, the high bf16's exponent bits land in the fp32
// exponent field -> ~1e34..Inf/NaN for any |v| in [0.047,3). 64 samples.
// ---------------------------------------------------------------------------
__global__ void k_detect(const u32* __restrict__ vol_u32, int* __restrict__ flag) {
    const int lane = threadIdx.x;           // 64 threads
    u32 x = vol_u32[lane];
    float v; __builtin_memcpy(&v, &x, 4);
    bool ok = fabsf(v) < 100.f;             // NaN/Inf compare false
    unsigned long long m = __ballot(ok);
    if (lane == 0) *flag = (m == ~0ull) ? 1 : 0;
}

// ---------------------------------------------------------------------------
// init: zero h0[buf0], h1[buf0], c0, c1; fill X0 latent cols; E/rate/s0.
// grid 2048 x 256 -> idx in [0, 524288)
// ---------------------------------------------------------------------------
__global__ __launch_bounds__(256) void k_init2(
    const void* __restrict__ ist, const void* __restrict__ lat,
    const void* __restrict__ vol, const void* __restrict__ thick, const void* __restrict__ trap,
    const int* __restrict__ dflag,
    u16* __restrict__ h0, u16* __restrict__ h1, u16* __restrict__ c0, u16* __restrict__ c1,
    u16* __restrict__ X0, float* __restrict__ Ee, float* __restrict__ ratep,
    float* __restrict__ sp, float* __restrict__ outE)
{
    const int f32 = *dflag;
    const int idx = blockIdx.x * 256 + threadIdx.x;
    h0[idx] = 0; h1[idx] = 0; c0[idx] = 0; c1[idx] = 0;
    if (idx < 262144) {
        int b = idx >> 8, k = idx & 255;
        X0[b * 257 + 1 + k] = f2b(gld(lat, idx, f32));
    }
    if (idx < 1024) {
        float E = gld(vol, idx, f32) / gld(thick, idx, f32);
        float Ea = gld(trap, idx * 8, f32), ga = gld(trap, idx * 8 + 1, f32);
        ratep[idx] = __expf(-fmaxf(Ea - ga * E, 0.f) / KB_T);
        Ee[idx] = E;
        sp[idx] = gld(ist, idx * 10 + 9, f32);
        outE[idx] = E;
    }
}

// ---------------------------------------------------------------------------
// pred/gen/bp + X0 s-column. grid 4 x 256.
// ---------------------------------------------------------------------------
__global__ __launch_bounds__(256) void k_pred(int t,
    const void* __restrict__ cW1, const void* __restrict__ cb1,
    const void* __restrict__ cW2, const void* __restrict__ cb2,
    const int* __restrict__ dflag,
    const float* __restrict__ Ee, const float* __restrict__ ratep, const float* __restrict__ sp,
    float* __restrict__ predb, u16* __restrict__ X0, float* __restrict__ out)
{
    const int f32 = *dflag;
    const int b = blockIdx.x * 256 + threadIdx.x;
    float sv = sp[b], Ev = Ee[b];
    float tv = 0.f;
    for (int l = 0; l < 32; ++l) {
        float z = sv * gld(cW1, l, f32) + Ev * gld(cW1, 32 + l, f32) + gld(cb1, l, f32);
        tv = fmaf(tanh_(z), gld(cW2, l, f32), tv);
    }
    float gen = ratep[b] * (1.f - sv);
    float pred = sv + gen + tv + gld(cb2, 0, f32);
    predb[b] = pred;
    X0[b * 257] = f2b(sv);
    out[OFF_GENS + b * 32 + t] = gen;
    out[OFF_BPS + b * 32 + t] = sigf(10.f * (pred - 0.5f));
}

// ---------------------------------------------------------------------------
// Simple LSTM cell: gates[b][g*512+j] = bias + X1@W1^T + X2@W2^T, then cell.
// X1/X2 are ws-resident bf16. W1 [2048][K1], W2 [2048][512], bias [2048]
// external (adaptive). grid dim3(2, 128) x 256: thread = j, 8 rows/block.
// ---------------------------------------------------------------------------
__global__ __launch_bounds__(256) void k_lstm_s(
    const u16* __restrict__ X1, int ldx1, int K1, const void* __restrict__ W1,
    const u16* __restrict__ X2, const void* __restrict__ W2,
    const void* __restrict__ bias, const int* __restrict__ dflag,
    u16* __restrict__ c, u16* __restrict__ hout)
{
    const int f32 = *dflag;
    const int j = blockIdx.x * 256 + threadIdx.x;   // [0,512)
    const int b0 = blockIdx.y * 8;
    float acc[4][8];
#pragma unroll
    for (int g = 0; g < 4; ++g) {
        float bg = gld(bias, g * 512 + j, f32);
#pragma unroll
        for (int i = 0; i < 8; ++i) acc[g][i] = bg;
    }
    for (int k = 0; k < K1; ++k) {
        float xa[8];
#pragma unroll
        for (int i = 0; i < 8; ++i) xa[i] = b2f(X1[(b0 + i) * ldx1 + k]);
#pragma unroll
        for (int g = 0; g < 4; ++g) {
            float w = gld(W1, (g * 512 + j) * K1 + k, f32);
#pragma unroll
            for (int i = 0; i < 8; ++i) acc[g][i] = fmaf(w, xa[i], acc[g][i]);
        }
    }
    for (int k = 0; k < 512; ++k) {
        float xa[8];
#pragma unroll
        for (int i = 0; i < 8; ++i) xa[i] = b2f(X2[(b0 + i) * 512 + k]);
#pragma unroll
        for (int g = 0; g < 4; ++g) {
            float w = gld(W2, (g * 512 + j) * 512 + k, f32);
#pragma unroll
            for (int i = 0; i < 8; ++i) acc[g][i] = fmaf(w, xa[i], acc[g][i]);
        }
    }
#pragma unroll
    for (int i = 0; i < 8; ++i) {
        int b = b0 + i;
        float cold = b2f(c[b * 512 + j]);
        float ig = sigf(acc[0][i]), fg = sigf(acc[1][i]);
        float gg = tanh_(acc[2][i]), og = sigf(acc[3][i]);
        float cn = fg * cold + ig * gg;
        c[b * 512 + j] = f2b(cn);
        hout[b * 512 + j] = f2b(og * tanh_(cn));
    }
}

// ---------------------------------------------------------------------------
// f1 = gelu(pred*fW1[0] + h1@fW1[1:] + fb1). fW1 k-major (513,256).
// grid 256 x 256: thread = n, 4 rows/block.
// ---------------------------------------------------------------------------
__global__ __launch_bounds__(256) void k_f1(
    const u16* __restrict__ h1n, const void* __restrict__ fW1, const void* __restrict__ fb1,
    const int* __restrict__ dflag, const float* __restrict__ predb, u16* __restrict__ F1)
{
    const int f32 = *dflag;
    const int n = threadIdx.x;
    const int b0 = blockIdx.x * 4;
    float w0 = gld(fW1, n, f32), bb = gld(fb1, n, f32);
    float acc[4];
#pragma unroll
    for (int i = 0; i < 4; ++i) acc[i] = bb + predb[b0 + i] * w0;
    for (int k = 0; k < 512; ++k) {
        float w = gld(fW1, (1 + k) * 256 + n, f32);
#pragma unroll
        for (int i = 0; i < 4; ++i) acc[i] = fmaf(w, b2f(h1n[(b0 + i) * 512 + k]), acc[i]);
    }
#pragma unroll
    for (int i = 0; i < 4; ++i) F1[(b0 + i) * 256 + n] = f2b(gelu_(acc[i]));
}

// ---------------------------------------------------------------------------
// f2 = gelu(f1@fW2 + fb2). fW2 k-major (256,256). grid 256 x 256.
// ---------------------------------------------------------------------------
__global__ __launch_bounds__(256) void k_f2(
    const u16* __restrict__ F1, const void* __restrict__ fW2, const void* __restrict__ fb2,
    const int* __restrict__ dflag, u16* __restrict__ F2)
{
    const int f32 = *dflag;
    const int n = threadIdx.x;
    const int b0 = blockIdx.x * 4;
    float bb = gld(fb2, n, f32);
    float acc[4];
#pragma unroll
    for (int i = 0; i < 4; ++i) acc[i] = bb;
    for (int k = 0; k < 256; ++k) {
        float w = gld(fW2, k * 256 + n, f32);
#pragma unroll
        for (int i = 0; i < 4; ++i) acc[i] = fmaf(w, b2f(F1[(b0 + i) * 256 + k]), acc[i]);
    }
#pragma unroll
    for (int i = 0; i < 4; ++i) F2[(b0 + i) * 256 + n] = f2b(gelu_(acc[i]));
}

// ---------------------------------------------------------------------------
// nxt = clip(max(s, f2@fW3 + fb3), 0, 1); s update + preds output. grid 4 x 256.
// ---------------------------------------------------------------------------
__global__ __launch_bounds__(256) void k_upd(int t,
    const u16* __restrict__ F2, const void* __restrict__ fW3, const void* __restrict__ fb3,
    const int* __restrict__ dflag, float* __restrict__ sp, float* __restrict__ out)
{
    const int f32 = *dflag;
    const int b = blockIdx.x * 256 + threadIdx.x;
    float p = gld(fb3, 0, f32);
    for (int k = 0; k < 256; ++k) p = fmaf(b2f(F2[b * 256 + k]), gld(fW3, k, f32), p);
    float sv = sp[b];
    float nxt = fminf(fmaxf(fmaxf(sv, p), 0.f), 1.f);
    sp[b] = nxt;
    out[b * 32 + t] = nxt;
}

// ---------------------------------------------------------------------------
extern "C" void kernel_launch(void* const* d_in, const int* in_sizes, int n_in,
                              void* d_out, int out_size, void* d_ws, size_t ws_size,
                              hipStream_t stream) {
    const void* ist   = d_in[0];
    const void* lat   = d_in[1];
    const void* vol   = d_in[2];
    const void* thick = d_in[3];
    const void* trap  = d_in[4];
    const void* W_ih0 = d_in[5];
    const void* W_hh0 = d_in[6];
    const void* b0_   = d_in[7];
    const void* W_ih1 = d_in[8];
    const void* W_hh1 = d_in[9];
    const void* b1_   = d_in[10];
    const void* fW1   = d_in[11];
    const void* fb1   = d_in[12];
    const void* fW2   = d_in[13];
    const void* fb2   = d_in[14];
    const void* fW3   = d_in[15];
    const void* fb3   = d_in[16];
    const void* cW1   = d_in[17];
    const void* cb1   = d_in[18];
    const void* cW2   = d_in[19];
    const void* cb2   = d_in[20];

    char* ws = (char*)d_ws;
    u16*   X0    = (u16*)(ws + WS_X0);
    float* predb = (float*)(ws + WS_PRD);
    float* Ee    = (float*)(ws + WS_EE);
    float* ratep = (float*)(ws + WS_RATE);
    float* sp    = (float*)(ws + WS_SP);
    u16*   h0    = (u16*)(ws + WS_H0);
    u16*   h1    = (u16*)(ws + WS_H1);
    u16*   c0    = (u16*)(ws + WS_C0);
    u16*   c1    = (u16*)(ws + WS_C1);
    u16*   F1    = (u16*)(ws + WS_F1);
    u16*   F2    = (u16*)(ws + WS_F2);
    int*   dflag = (int*)(ws + WS_FLAG);
    float* out   = (float*)d_out;

    k_detect<<<1, 64, 0, stream>>>((const u32*)vol, dflag);
    k_init2<<<2048, 256, 0, stream>>>(ist, lat, vol, thick, trap, dflag,
                                      h0, h1, c0, c1, X0, Ee, ratep, sp, out + OFF_E);

    for (int t = 0; t < 32; ++t) {
        int cur = t & 1, nx = cur ^ 1;
        k_pred<<<4, 256, 0, stream>>>(t, cW1, cb1, cW2, cb2, dflag,
                                      Ee, ratep, sp, predb, X0, out);
        k_lstm_s<<<dim3(2, 128), 256, 0, stream>>>(X0, 257, 257, W_ih0,
                                                   h0 + cur * HS, W_hh0, b0_, dflag,
                                                   c0, h0 + nx * HS);
        k_lstm_s<<<dim3(2, 128), 256, 0, stream>>>(h0 + nx * HS, 512, 512, W_ih1,
                                                   h1 + cur * HS, W_hh1, b1_, dflag,
                                                   c1, h1 + nx * HS);
        k_f1<<<256, 256, 0, stream>>>(h1 + nx * HS, fW1, fb1, dflag, predb, F1);
        k_f2<<<256, 256, 0, stream>>>(F1, fW2, fb2, dflag, F2);
        k_upd<<<4, 256, 0, stream>>>(t, F2, fW3, fb3, dflag, sp, out);
    }
}

// Round 6
// 4901.698 us; speedup vs baseline: 13.1311x; 13.1311x over previous
//
#include <hip/hip_runtime.h>
#include <hip/hip_bf16.h>

typedef unsigned short u16;
typedef unsigned int u32;
typedef __attribute__((ext_vector_type(8))) short bh8;     // 8 x bf16 MFMA A/B frag
typedef __attribute__((ext_vector_type(4))) float f32x4;   // MFMA C/D frag

#define KB_T 0.025851f
#define HS (1024 * 512)

// d_out (fp32): preds.T [1024][32] | E [1024] | gens.T [1024][32] | bps.T [1024][32]
#define OFF_E    32768
#define OFF_GENS 33792
#define OFF_BPS  66560

// ---- workspace layout (byte offsets); base total 7,364,608 B (< proven 7.88MB)
#define WS_WP     0u         // [2048][256] bf16  (W_ih0[:,1:])
#define WS_W0COL  1048576u   // [2048] f32        (W_ih0[:,0])
#define WS_EE     1056768u   // [1024] f32
#define WS_RATE   1060864u   // [1024] f32
#define WS_SP     1064960u   // [1024] f32
#define WS_PRD    1069056u   // [1024] f32
#define WS_H0     1073152u   // 2x[1024][512] bf16 ping-pong (dead half doubles as F1|F2)
#define WS_H1     3170304u   // 2x[1024][512] bf16
#define WS_C0     5267456u   // [1024][512] bf16
#define WS_C1     6316032u   // [1024][512] bf16
#define WS_BASE_END 7364608u
// optional extension (only if ws_size allows): pre-converted bf16 weights
#define WS_WHH0B  7364608u   // [2048][512] bf16
#define WS_WIH1B  9461760u
#define WS_WHH1B  11558912u
#define WS_EXT_END 13656064u

__device__ __forceinline__ float b2f(u16 u) { u32 x = ((u32)u) << 16; float f; __builtin_memcpy(&f, &x, 4); return f; }
__device__ __forceinline__ u16 f2b(float f) { __hip_bfloat16 h = __float2bfloat16(f); u16 u; __builtin_memcpy(&u, &h, 2); return u; }
__device__ __forceinline__ float sigf(float x) { return 1.f / (1.f + __expf(-x)); }
__device__ __forceinline__ float tanh_(float x) { return 1.f - 2.f / (__expf(2.f * x) + 1.f); }
__device__ __forceinline__ float gelu_(float x) { return 0.5f * x * (1.f + tanh_(0.7978845608f * (x + 0.044715f * x * x * x))); }

// stage 8 contiguous elements into LDS as bf16; src is bf16 (16B copy) or fp32 (32B + convert)
__device__ __forceinline__ void stage8(u16* dst, const void* src, int ofs, int srcf32) {
    if (srcf32) {
        const float* s = (const float*)src + ofs;
        float4 a = *(const float4*)s;
        float4 b = *(const float4*)(s + 4);
        u16 t[8] = {f2b(a.x), f2b(a.y), f2b(a.z), f2b(a.w),
                    f2b(b.x), f2b(b.y), f2b(b.z), f2b(b.w)};
        *(float4*)dst = *(const float4*)t;
    } else {
        *(float4*)dst = *(const float4*)((const u16*)src + ofs);
    }
}

// ---------------------------------------------------------------------------
// setup: zero h0[0],h1[0],c0,c1; repack W_ih0 -> Wp(bf16)+w0col(f32); E/rate/s0.
// grid 2048 x 256 -> idx in [0, 524288)
// ---------------------------------------------------------------------------
__global__ __launch_bounds__(256) void k_setup(
    const float* __restrict__ ist, const float* __restrict__ vol, const float* __restrict__ thick,
    const float* __restrict__ trap, const float* __restrict__ W_ih0,
    u16* __restrict__ h0, u16* __restrict__ h1, u16* __restrict__ c0, u16* __restrict__ c1,
    u16* __restrict__ Wp, float* __restrict__ w0col,
    float* __restrict__ Ee, float* __restrict__ ratep, float* __restrict__ sp,
    float* __restrict__ outE)
{
    const int idx = blockIdx.x * 256 + threadIdx.x;
    h0[idx] = 0; h1[idx] = 0; c0[idx] = 0; c1[idx] = 0;
    Wp[idx] = f2b(W_ih0[(idx >> 8) * 257 + 1 + (idx & 255)]);
    if (idx < 2048) w0col[idx] = W_ih0[idx * 257];
    if (idx < 1024) {
        float E = vol[idx] / thick[idx];
        float Ea = trap[idx * 8], ga = trap[idx * 8 + 1];
        ratep[idx] = __expf(-fmaxf(Ea - ga * E, 0.f) / KB_T);
        Ee[idx] = E;
        sp[idx] = ist[idx * 10 + 9];
        outE[idx] = E;
    }
}

// optional: fp32 -> bf16 convert of the three K=512 LSTM weights. grid 4096 x 256.
__global__ __launch_bounds__(256) void k_conv3(
    const float* __restrict__ a, const float* __restrict__ b, const float* __restrict__ c,
    u16* __restrict__ oa, u16* __restrict__ ob, u16* __restrict__ oc)
{
    const int idx = blockIdx.x * 256 + threadIdx.x;   // [0, 1048576)
    oa[idx] = f2b(a[idx]); ob[idx] = f2b(b[idx]); oc[idx] = f2b(c[idx]);
}

// ---------------------------------------------------------------------------
// pred/gen/bp. grid 4 x 256. (proven in R5; fp32 inputs hard-coded)
// ---------------------------------------------------------------------------
__global__ __launch_bounds__(256) void k_pred(int t,
    const float* __restrict__ cW1, const float* __restrict__ cb1,
    const float* __restrict__ cW2, const float* __restrict__ cb2,
    const float* __restrict__ Ee, const float* __restrict__ ratep, const float* __restrict__ sp,
    float* __restrict__ predb, float* __restrict__ out)
{
    const int b = blockIdx.x * 256 + threadIdx.x;
    float sv = sp[b], Ev = Ee[b];
    float tv = 0.f;
    for (int l = 0; l < 32; ++l) {
        float z = sv * cW1[l] + Ev * cW1[32 + l] + cb1[l];
        tv = fmaf(tanh_(z), cW2[l], tv);
    }
    float gen = ratep[b] * (1.f - sv);
    float pred = sv + gen + tv + cb2[0];
    predb[b] = pred;
    out[OFF_GENS + b * 32 + t] = gen;
    out[OFF_BPS + b * 32 + t] = sigf(10.f * (pred - 0.5f));
}

// ---------------------------------------------------------------------------
// MFMA LSTM cell. gates[b][g*512+j] = bias + A1@W1^T + A2@W2^T  [+ s*w0col]
// Tile 64 rows x 32 j (=128 gate cols); waves 2x2 each 32x64.
// A1 bf16; A2/W1/W2 fp32-or-bf16 (flag); bias fp32; c bf16 in/out; hout bf16.
// grid dim3(16,16) x 256.
// ---------------------------------------------------------------------------
__global__ __launch_bounds__(256) void k_lstm_m(
    const u16* __restrict__ A1, int lda1, int nk1, const void* __restrict__ W1, int ldw1, int w1f,
    const void* __restrict__ A2, int a2f, int lda2, int nk2, const void* __restrict__ W2, int ldw2, int w2f,
    const float* __restrict__ w0col, const float* __restrict__ s, const float* __restrict__ bias,
    u16* __restrict__ c, u16* __restrict__ hout)
{
    __shared__ __attribute__((aligned(16))) u16 ldsA[64 * 64];
    __shared__ __attribute__((aligned(16))) u16 ldsB[128 * 64];
    __shared__ float gbuf[64 * 132];   // stride 132: only 2-way bank aliasing (free)

    const int tid = threadIdx.x, wid = tid >> 6, lane = tid & 63;
    const int q = lane >> 4, ln = lane & 15;
    const int wr = wid >> 1, wc = wid & 1;
    const int j0 = blockIdx.x * 32, row0 = blockIdx.y * 64;

    f32x4 acc[2][4];
#pragma unroll
    for (int a = 0; a < 2; a++)
#pragma unroll
        for (int b = 0; b < 4; b++) acc[a][b] = f32x4{0.f, 0.f, 0.f, 0.f};

    for (int half = 0; half < 2; ++half) {
        const void* A = half ? A2 : (const void*)A1;
        const void* W = half ? W2 : W1;
        const int lda = half ? lda2 : lda1, ldw = half ? ldw2 : ldw1;
        const int nk = half ? nk2 : nk1;
        const int af = half ? a2f : 0;
        const int wf = half ? w2f : w1f;
        for (int kc = 0; kc < nk; ++kc) {
            const int k0 = kc * 64;
            __syncthreads();
#pragma unroll
            for (int it = 0; it < 2; ++it) {
                int chn = tid + it * 256, r = chn >> 3, cl = (chn & 7) * 8;
                stage8(ldsA + r * 64 + cl, A, (row0 + r) * lda + k0 + cl, af);
            }
#pragma unroll
            for (int it = 0; it < 4; ++it) {
                int chn = tid + it * 256, m = chn >> 3, cl = (chn & 7) * 8;
                int wrow = (m >> 5) * 512 + j0 + (m & 31);   // gate (m>>5), col j
                stage8(ldsB + m * 64 + cl, W, wrow * ldw + k0 + cl, wf);
            }
            __syncthreads();
#pragma unroll
            for (int ks = 0; ks < 2; ++ks) {
                const int kk = ks * 32 + q * 8;
                bh8 afr[2], bfr[4];
#pragma unroll
                for (int rt = 0; rt < 2; ++rt) afr[rt] = *(const bh8*)(ldsA + (wr * 32 + rt * 16 + ln) * 64 + kk);
#pragma unroll
                for (int nt = 0; nt < 4; ++nt) bfr[nt] = *(const bh8*)(ldsB + (wc * 64 + nt * 16 + ln) * 64 + kk);
#pragma unroll
                for (int rt = 0; rt < 2; ++rt)
#pragma unroll
                    for (int nt = 0; nt < 4; ++nt)
                        acc[rt][nt] = __builtin_amdgcn_mfma_f32_16x16x32_bf16(afr[rt], bfr[nt], acc[rt][nt], 0, 0, 0);
            }
        }
    }
    __syncthreads();
    // C/D layout (measured m89/m91): col = lane&15, row = (lane>>4)*4 + reg
#pragma unroll
    for (int rt = 0; rt < 2; ++rt)
#pragma unroll
        for (int nt = 0; nt < 4; ++nt)
#pragma unroll
            for (int r = 0; r < 4; ++r) {
                int lrow = wr * 32 + rt * 16 + q * 4 + r;
                int lcol = wc * 64 + nt * 16 + ln;
                gbuf[lrow * 132 + lcol] = acc[rt][nt][r];
            }
    __syncthreads();
#pragma unroll
    for (int p = 0; p < 8; ++p) {
        int idx = p * 256 + tid;
        int bl = idx >> 5, j = idx & 31;
        int bg = row0 + bl, jg = j0 + j;
        float gi = gbuf[bl * 132 +  0 + j] + bias[jg];
        float gf = gbuf[bl * 132 + 32 + j] + bias[512 + jg];
        float gg = gbuf[bl * 132 + 64 + j] + bias[1024 + jg];
        float go = gbuf[bl * 132 + 96 + j] + bias[1536 + jg];
        if (w0col) {
            float sv = s[bg];
            gi += sv * w0col[jg];         gf += sv * w0col[512 + jg];
            gg += sv * w0col[1024 + jg];  go += sv * w0col[1536 + jg];
        }
        float cold = b2f(c[bg * 512 + jg]);
        float cn = sigf(gf) * cold + sigf(gi) * tanh_(gg);
        float hn = sigf(go) * tanh_(cn);
        c[bg * 512 + jg] = f2b(cn);
        hout[bg * 512 + jg] = f2b(hn);
    }
}

// ---------------------------------------------------------------------------
// f1 = gelu(pred*fW1[0] + h1@fW1[1:] + fb1). fW1 fp32 k-major (513,256).
// grid 256 x 256. (proven in R5)
// ---------------------------------------------------------------------------
__global__ __launch_bounds__(256) void k_f1(
    const u16* __restrict__ h1n, const float* __restrict__ fW1, const float* __restrict__ fb1,
    const float* __restrict__ predb, u16* __restrict__ F1)
{
    const int n = threadIdx.x;
    const int b0 = blockIdx.x * 4;
    float w0 = fW1[n], bb = fb1[n];
    float acc[4];
#pragma unroll
    for (int i = 0; i < 4; ++i) acc[i] = bb + predb[b0 + i] * w0;
    for (int k = 0; k < 512; ++k) {
        float w = fW1[(1 + k) * 256 + n];
#pragma unroll
        for (int i = 0; i < 4; ++i) acc[i] = fmaf(w, b2f(h1n[(b0 + i) * 512 + k]), acc[i]);
    }
#pragma unroll
    for (int i = 0; i < 4; ++i) F1[(b0 + i) * 256 + n] = f2b(gelu_(acc[i]));
}

// ---------------------------------------------------------------------------
// f2 = gelu(f1@fW2 + fb2). fW2 fp32 k-major (256,256). grid 256 x 256. (proven)
// ---------------------------------------------------------------------------
__global__ __launch_bounds__(256) void k_f2(
    const u16* __restrict__ F1, const float* __restrict__ fW2, const float* __restrict__ fb2,
    u16* __restrict__ F2)
{
    const int n = threadIdx.x;
    const int b0 = blockIdx.x * 4;
    float bb = fb2[n];
    float acc[4];
#pragma unroll
    for (int i = 0; i < 4; ++i) acc[i] = bb;
    for (int k = 0; k < 256; ++k) {
        float w = fW2[k * 256 + n];
#pragma unroll
        for (int i = 0; i < 4; ++i) acc[i] = fmaf(w, b2f(F1[(b0 + i) * 256 + k]), acc[i]);
    }
#pragma unroll
    for (int i = 0; i < 4; ++i) F2[(b0 + i) * 256 + n] = f2b(gelu_(acc[i]));
}

// ---------------------------------------------------------------------------
// nxt = clip(max(s, f2@fW3 + fb3), 0, 1); s update + preds. grid 4 x 256. (proven)
// ---------------------------------------------------------------------------
__global__ __launch_bounds__(256) void k_upd(int t,
    const u16* __restrict__ F2, const float* __restrict__ fW3, const float* __restrict__ fb3,
    float* __restrict__ sp, float* __restrict__ out)
{
    const int b = blockIdx.x * 256 + threadIdx.x;
    float p = fb3[0];
    for (int k = 0; k < 256; ++k) p = fmaf(b2f(F2[b * 256 + k]), fW3[k], p);
    float sv = sp[b];
    float nxt = fminf(fmaxf(fmaxf(sv, p), 0.f), 1.f);
    sp[b] = nxt;
    out[b * 32 + t] = nxt;
}

// ---------------------------------------------------------------------------
extern "C" void kernel_launch(void* const* d_in, const int* in_sizes, int n_in,
                              void* d_out, int out_size, void* d_ws, size_t ws_size,
                              hipStream_t stream) {
    const float* ist   = (const float*)d_in[0];
    const float* lat   = (const float*)d_in[1];
    const float* vol   = (const float*)d_in[2];
    const float* thick = (const float*)d_in[3];
    const float* trap  = (const float*)d_in[4];
    const float* W_ih0 = (const float*)d_in[5];
    const float* W_hh0 = (const float*)d_in[6];
    const float* b0_   = (const float*)d_in[7];
    const float* W_ih1 = (const float*)d_in[8];
    const float* W_hh1 = (const float*)d_in[9];
    const float* b1_   = (const float*)d_in[10];
    const float* fW1   = (const float*)d_in[11];
    const float* fb1   = (const float*)d_in[12];
    const float* fW2   = (const float*)d_in[13];
    const float* fb2   = (const float*)d_in[14];
    const float* fW3   = (const float*)d_in[15];
    const float* fb3   = (const float*)d_in[16];
    const float* cW1   = (const float*)d_in[17];
    const float* cb1   = (const float*)d_in[18];
    const float* cW2   = (const float*)d_in[19];
    const float* cb2   = (const float*)d_in[20];

    char* ws = (char*)d_ws;
    u16*   Wp    = (u16*)(ws + WS_WP);
    float* w0col = (float*)(ws + WS_W0COL);
    float* Ee    = (float*)(ws + WS_EE);
    float* ratep = (float*)(ws + WS_RATE);
    float* sp    = (float*)(ws + WS_SP);
    float* predb = (float*)(ws + WS_PRD);
    u16*   h0    = (u16*)(ws + WS_H0);
    u16*   h1    = (u16*)(ws + WS_H1);
    u16*   c0    = (u16*)(ws + WS_C0);
    u16*   c1    = (u16*)(ws + WS_C1);
    float* out   = (float*)d_out;

    const bool big = ws_size >= (size_t)WS_EXT_END;
    u16* whh0b = (u16*)(ws + WS_WHH0B);
    u16* wih1b = (u16*)(ws + WS_WIH1B);
    u16* whh1b = (u16*)(ws + WS_WHH1B);

    k_setup<<<2048, 256, 0, stream>>>(ist, vol, thick, trap, W_ih0,
        h0, h1, c0, c1, Wp, w0col, Ee, ratep, sp, out + OFF_E);
    if (big)
        k_conv3<<<4096, 256, 0, stream>>>(W_hh0, W_ih1, W_hh1, whh0b, wih1b, whh1b);

    const void* pWhh0 = big ? (const void*)whh0b : (const void*)W_hh0;
    const void* pWih1 = big ? (const void*)wih1b : (const void*)W_ih1;
    const void* pWhh1 = big ? (const void*)whh1b : (const void*)W_hh1;
    const int wf = big ? 0 : 1;

    for (int t = 0; t < 32; ++t) {
        int cur = t & 1, nx = cur ^ 1;
        k_pred<<<4, 256, 0, stream>>>(t, cW1, cb1, cW2, cb2, Ee, ratep, sp, predb, out);
        // lstm0: h0@W_hh0^T (K=512) + lat@Wp^T (K=256) + s*w0col + b0
        k_lstm_m<<<dim3(16, 16), 256, 0, stream>>>(
            h0 + cur * HS, 512, 8, pWhh0, 512, wf,
            lat, 1, 256, 4, Wp, 256, 0,
            w0col, sp, b0_, c0, h0 + nx * HS);
        // lstm1: h0n@W_ih1^T + h1@W_hh1^T + b1
        k_lstm_m<<<dim3(16, 16), 256, 0, stream>>>(
            h0 + nx * HS, 512, 8, pWih1, 512, wf,
            h1 + cur * HS, 0, 512, 8, pWhh1, 512, wf,
            (const float*)nullptr, (const float*)nullptr, b1_, c1, h1 + nx * HS);
        // F1|F2 overlay the dead h0[cur] half (1MB): F1 [1024][256], F2 [1024][256]
        u16* F1 = h0 + cur * HS;
        u16* F2 = F1 + 262144;
        k_f1<<<256, 256, 0, stream>>>(h1 + nx * HS, fW1, fb1, predb, F1);
        k_f2<<<256, 256, 0, stream>>>(F1, fW2, fb2, F2);
        k_upd<<<4, 256, 0, stream>>>(t, F2, fW3, fb3, sp, out);
    }
}

// Round 7
// 3177.555 us; speedup vs baseline: 20.2560x; 1.5426x over previous
//
#include <hip/hip_runtime.h>
#include <hip/hip_bf16.h>

typedef unsigned short u16;
typedef unsigned int u32;
typedef __attribute__((ext_vector_type(8))) short bh8;     // 8 x bf16 MFMA A/B frag
typedef __attribute__((ext_vector_type(4))) float f32x4;   // MFMA C/D frag

#define KB_T 0.025851f
#define HS (1024 * 512)

// d_out (fp32): preds.T [1024][32] | E [1024] | gens.T [1024][32] | bps.T [1024][32]
#define OFF_E    32768
#define OFF_GENS 33792
#define OFF_BPS  66560

// ---- workspace layout (byte offsets); base total 7,754,752 B (< proven 7.88MB)
#define WS_WP     0u         // [2048][256] bf16  (W_ih0[:,1:])
#define WS_FW1T   1048576u   // [256][512] bf16   (fW1[1:] ^T)
#define WS_FW2T   1310720u   // [256][256] bf16   (fW2 ^T)
#define WS_FW1R0  1441792u   // [256] f32         (fW1 row 0)
#define WS_W0COL  1442816u   // [2048] f32        (W_ih0[:,0])
#define WS_EE     1451008u   // [1024] f32
#define WS_RATE   1455104u   // [1024] f32
#define WS_SP     1459200u   // [1024] f32
#define WS_H0     1463296u   // 2x[1024][512] bf16 ping-pong
#define WS_H1     3560448u   // 2x[1024][512] bf16
#define WS_C0     5657600u   // [1024][512] bf16
#define WS_C1     6706176u   // [1024][512] bf16
#define WS_BASE_END 7754752u
// optional extension: pre-converted bf16 LSTM weights (halves staging traffic)
#define WS_WHH0B  7754752u
#define WS_WIH1B  9851904u
#define WS_WHH1B  11949056u
#define WS_EXT_END 14046208u

__device__ __forceinline__ float b2f(u16 u) { u32 x = ((u32)u) << 16; float f; __builtin_memcpy(&f, &x, 4); return f; }
__device__ __forceinline__ u16 f2b(float f) { __hip_bfloat16 h = __float2bfloat16(f); u16 u; __builtin_memcpy(&u, &h, 2); return u; }
__device__ __forceinline__ float sigf(float x) { return 1.f / (1.f + __expf(-x)); }
__device__ __forceinline__ float tanh_(float x) { return 1.f - 2.f / (__expf(2.f * x) + 1.f); }
__device__ __forceinline__ float gelu_(float x) { return 0.5f * x * (1.f + tanh_(0.7978845608f * (x + 0.044715f * x * x * x))); }

// stage 8 contiguous elements into LDS as bf16; src bf16 (16B copy) or fp32 (32B + cvt)
__device__ __forceinline__ void stage8(u16* dst, const void* src, int ofs, int srcf32) {
    if (srcf32) {
        const float* s = (const float*)src + ofs;
        float4 a = *(const float4*)s;
        float4 b = *(const float4*)(s + 4);
        u16 t[8] = {f2b(a.x), f2b(a.y), f2b(a.z), f2b(a.w),
                    f2b(b.x), f2b(b.y), f2b(b.z), f2b(b.w)};
        *(float4*)dst = *(const float4*)t;
    } else {
        *(float4*)dst = *(const float4*)((const u16*)src + ofs);
    }
}

// ---------------------------------------------------------------------------
// setup: zero h0[0],h1[0],c0,c1; repack W_ih0 -> Wp+w0col; fW1 -> fW1t+fw1r0;
// fW2 -> fW2t; E/rate/s0. grid 2048 x 256 -> idx in [0, 524288)
// ---------------------------------------------------------------------------
__global__ __launch_bounds__(256) void k_setup(
    const float* __restrict__ ist, const float* __restrict__ vol, const float* __restrict__ thick,
    const float* __restrict__ trap, const float* __restrict__ W_ih0,
    const float* __restrict__ fW1, const float* __restrict__ fW2,
    u16* __restrict__ h0, u16* __restrict__ h1, u16* __restrict__ c0, u16* __restrict__ c1,
    u16* __restrict__ Wp, float* __restrict__ w0col,
    u16* __restrict__ fW1t, u16* __restrict__ fW2t, float* __restrict__ fw1r0,
    float* __restrict__ Ee, float* __restrict__ ratep, float* __restrict__ sp,
    float* __restrict__ outE)
{
    const int idx = blockIdx.x * 256 + threadIdx.x;
    h0[idx] = 0; h1[idx] = 0; c0[idx] = 0; c1[idx] = 0;
    Wp[idx] = f2b(W_ih0[(idx >> 8) * 257 + 1 + (idx & 255)]);
    if (idx < 131072) { int n = idx >> 9, k = idx & 511; fW1t[n * 512 + k] = f2b(fW1[(1 + k) * 256 + n]); }
    if (idx < 65536)  { int n = idx >> 8, k = idx & 255; fW2t[n * 256 + k] = f2b(fW2[k * 256 + n]); }
    if (idx < 2048)   w0col[idx] = W_ih0[idx * 257];
    if (idx < 256)    fw1r0[idx] = fW1[idx];
    if (idx < 1024) {
        float E = vol[idx] / thick[idx];
        float Ea = trap[idx * 8], ga = trap[idx * 8 + 1];
        ratep[idx] = __expf(-fmaxf(Ea - ga * E, 0.f) / KB_T);
        Ee[idx] = E;
        sp[idx] = ist[idx * 10 + 9];
        outE[idx] = E;
    }
}

// optional: fp32 -> bf16 convert of the three K=512 LSTM weights. grid 4096 x 256.
__global__ __launch_bounds__(256) void k_conv3(
    const float* __restrict__ a, const float* __restrict__ b, const float* __restrict__ c,
    u16* __restrict__ oa, u16* __restrict__ ob, u16* __restrict__ oc)
{
    const int idx = blockIdx.x * 256 + threadIdx.x;   // [0, 1048576)
    oa[idx] = f2b(a[idx]); ob[idx] = f2b(b[idx]); oc[idx] = f2b(c[idx]);
}

// ---------------------------------------------------------------------------
// MFMA LSTM cell (proven R6). gates = bias + A1@W1^T + A2@W2^T [+ s*w0col].
// Tile 64 rows x 32 j (=128 gate cols); waves 2x2. grid dim3(16,16) x 256.
// gbuf overlays ldsA/ldsB (used only after the post-K-loop barrier): 33KB LDS.
// ---------------------------------------------------------------------------
__global__ __launch_bounds__(256) void k_lstm_m(
    const u16* __restrict__ A1, int lda1, int nk1, const void* __restrict__ W1, int ldw1, int w1f,
    const void* __restrict__ A2, int a2f, int lda2, int nk2, const void* __restrict__ W2, int ldw2, int w2f,
    const float* __restrict__ w0col, const float* __restrict__ s, const float* __restrict__ bias,
    u16* __restrict__ c, u16* __restrict__ hout)
{
    __shared__ __attribute__((aligned(16))) char smem[64 * 132 * 4];  // 33792 B
    u16*   ldsA = (u16*)smem;                // [64*64] u16, 8KB
    u16*   ldsB = (u16*)(smem + 8192);       // [128*64] u16, 16KB
    float* gbuf = (float*)smem;              // [64*132] f32, overlaid (post-barrier use)

    const int tid = threadIdx.x, wid = tid >> 6, lane = tid & 63;
    const int q = lane >> 4, ln = lane & 15;
    const int wr = wid >> 1, wc = wid & 1;
    const int j0 = blockIdx.x * 32, row0 = blockIdx.y * 64;

    f32x4 acc[2][4];
#pragma unroll
    for (int a = 0; a < 2; a++)
#pragma unroll
        for (int b = 0; b < 4; b++) acc[a][b] = f32x4{0.f, 0.f, 0.f, 0.f};

    for (int half = 0; half < 2; ++half) {
        const void* A = half ? A2 : (const void*)A1;
        const void* W = half ? W2 : W1;
        const int lda = half ? lda2 : lda1, ldw = half ? ldw2 : ldw1;
        const int nk = half ? nk2 : nk1;
        const int af = half ? a2f : 0;
        const int wf = half ? w2f : w1f;
        for (int kc = 0; kc < nk; ++kc) {
            const int k0 = kc * 64;
            __syncthreads();
#pragma unroll
            for (int it = 0; it < 2; ++it) {
                int chn = tid + it * 256, r = chn >> 3, cl = (chn & 7) * 8;
                stage8(ldsA + r * 64 + cl, A, (row0 + r) * lda + k0 + cl, af);
            }
#pragma unroll
            for (int it = 0; it < 4; ++it) {
                int chn = tid + it * 256, m = chn >> 3, cl = (chn & 7) * 8;
                int wrow = (m >> 5) * 512 + j0 + (m & 31);   // gate (m>>5), col j
                stage8(ldsB + m * 64 + cl, W, wrow * ldw + k0 + cl, wf);
            }
            __syncthreads();
#pragma unroll
            for (int ks = 0; ks < 2; ++ks) {
                const int kk = ks * 32 + q * 8;
                bh8 afr[2], bfr[4];
#pragma unroll
                for (int rt = 0; rt < 2; ++rt) afr[rt] = *(const bh8*)(ldsA + (wr * 32 + rt * 16 + ln) * 64 + kk);
#pragma unroll
                for (int nt = 0; nt < 4; ++nt) bfr[nt] = *(const bh8*)(ldsB + (wc * 64 + nt * 16 + ln) * 64 + kk);
#pragma unroll
                for (int rt = 0; rt < 2; ++rt)
#pragma unroll
                    for (int nt = 0; nt < 4; ++nt)
                        acc[rt][nt] = __builtin_amdgcn_mfma_f32_16x16x32_bf16(afr[rt], bfr[nt], acc[rt][nt], 0, 0, 0);
            }
        }
    }
    __syncthreads();
    // C/D layout (measured m89/m91): col = lane&15, row = (lane>>4)*4 + reg
#pragma unroll
    for (int rt = 0; rt < 2; ++rt)
#pragma unroll
        for (int nt = 0; nt < 4; ++nt)
#pragma unroll
            for (int r = 0; r < 4; ++r) {
                int lrow = wr * 32 + rt * 16 + q * 4 + r;
                int lcol = wc * 64 + nt * 16 + ln;
                gbuf[lrow * 132 + lcol] = acc[rt][nt][r];
            }
    __syncthreads();
#pragma unroll
    for (int p = 0; p < 8; ++p) {
        int idx = p * 256 + tid;
        int bl = idx >> 5, j = idx & 31;
        int bg = row0 + bl, jg = j0 + j;
        float gi = gbuf[bl * 132 +  0 + j] + bias[jg];
        float gf = gbuf[bl * 132 + 32 + j] + bias[512 + jg];
        float gg = gbuf[bl * 132 + 64 + j] + bias[1024 + jg];
        float go = gbuf[bl * 132 + 96 + j] + bias[1536 + jg];
        if (w0col) {
            float sv = s[bg];
            gi += sv * w0col[jg];         gf += sv * w0col[512 + jg];
            gg += sv * w0col[1024 + jg];  go += sv * w0col[1536 + jg];
        }
        float cold = b2f(c[bg * 512 + jg]);
        float cn = sigf(gf) * cold + sigf(gi) * tanh_(gg);
        float hn = sigf(go) * tanh_(cn);
        c[bg * 512 + jg] = f2b(cn);
        hout[bg * 512 + jg] = f2b(hn);
    }
}

// ---------------------------------------------------------------------------
// Fused f-net: pred/gen/bp + f1(MFMA) + f2(MFMA) + f3 dot + state update.
// 16 rows/WG, 64 WGs, 256 threads. Fragment indexing copied from k_lstm_m.
// ---------------------------------------------------------------------------
__global__ __launch_bounds__(256) void k_fnet(
    int t,
    const u16* __restrict__ h1n, const u16* __restrict__ fW1t, const float* __restrict__ fw1r0,
    const float* __restrict__ fb1, const u16* __restrict__ fW2t, const float* __restrict__ fb2,
    const float* __restrict__ fW3, const float* __restrict__ fb3,
    const float* __restrict__ cW1, const float* __restrict__ cb1,
    const float* __restrict__ cW2, const float* __restrict__ cb2,
    const float* __restrict__ Ee, const float* __restrict__ ratep,
    float* __restrict__ sp, float* __restrict__ out)
{
    __shared__ __attribute__((aligned(16))) u16 ldsA[16 * 64];     // 2KB
    __shared__ __attribute__((aligned(16))) u16 ldsB[256 * 64];    // 32KB
    __shared__ __attribute__((aligned(16))) u16 f1buf[16 * 256];   // 8KB
    __shared__ __attribute__((aligned(16))) float f2buf[16 * 256]; // 16KB
    __shared__ float predb[16];

    const int tid = threadIdx.x, wid = tid >> 6, lane = tid & 63;
    const int q = lane >> 4, ln = lane & 15;
    const int row0 = blockIdx.x * 16;

    // phase 0: pred/gen/bp (R5-proven math; 32 lanes per row, 2 rows/wave/pass)
#pragma unroll
    for (int pass = 0; pass < 2; ++pass) {
        int rl = wid * 4 + pass * 2 + (lane >> 5);
        int l = lane & 31;
        int bg = row0 + rl;
        float sv = sp[bg], Ev = Ee[bg];
        float z = sv * cW1[l] + Ev * cW1[32 + l] + cb1[l];
        float tv = tanh_(z) * cW2[l];
        tv += __shfl_xor(tv, 1); tv += __shfl_xor(tv, 2); tv += __shfl_xor(tv, 4);
        tv += __shfl_xor(tv, 8); tv += __shfl_xor(tv, 16);
        float gen = ratep[bg] * (1.f - sv);
        float pred = sv + gen + tv + cb2[0];
        if (l == 0) {
            predb[rl] = pred;
            out[OFF_GENS + bg * 32 + t] = gen;
            out[OFF_BPS + bg * 32 + t] = sigf(10.f * (pred - 0.5f));
        }
    }

    // phase 1: f1 = gelu(pred*fw1r0 + h1@fW1t^T + fb1), K=512
    f32x4 acc1[4];
#pragma unroll
    for (int b = 0; b < 4; b++) acc1[b] = f32x4{0.f, 0.f, 0.f, 0.f};
    for (int kc = 0; kc < 8; ++kc) {
        const int k0 = kc * 64;
        __syncthreads();
        if (tid < 128) {
            int r = tid >> 3, cl = (tid & 7) * 8;
            *(float4*)(ldsA + r * 64 + cl) = *(const float4*)(h1n + (row0 + r) * 512 + k0 + cl);
        }
#pragma unroll
        for (int it = 0; it < 8; ++it) {
            int chn = tid + it * 256, m = chn >> 3, cl = (chn & 7) * 8;
            *(float4*)(ldsB + m * 64 + cl) = *(const float4*)(fW1t + m * 512 + k0 + cl);
        }
        __syncthreads();
#pragma unroll
        for (int ks = 0; ks < 2; ++ks) {
            const int kk = ks * 32 + q * 8;
            bh8 a = *(const bh8*)(ldsA + ln * 64 + kk);
#pragma unroll
            for (int nt = 0; nt < 4; ++nt) {
                bh8 b = *(const bh8*)(ldsB + (wid * 64 + nt * 16 + ln) * 64 + kk);
                acc1[nt] = __builtin_amdgcn_mfma_f32_16x16x32_bf16(a, b, acc1[nt], 0, 0, 0);
            }
        }
    }
    __syncthreads();
#pragma unroll
    for (int nt = 0; nt < 4; ++nt)
#pragma unroll
        for (int r = 0; r < 4; ++r) {
            int row = q * 4 + r;
            int col = wid * 64 + nt * 16 + ln;
            float x = acc1[nt][r] + fb1[col] + predb[row] * fw1r0[col];
            f1buf[row * 256 + col] = f2b(gelu_(x));
        }

    // phase 2: f2 = gelu(f1@fW2t^T + fb2), K=256 (A from f1buf in LDS)
    f32x4 acc2[4];
#pragma unroll
    for (int b = 0; b < 4; b++) acc2[b] = f32x4{0.f, 0.f, 0.f, 0.f};
    for (int kc = 0; kc < 4; ++kc) {
        const int k0 = kc * 64;
        __syncthreads();
#pragma unroll
        for (int it = 0; it < 8; ++it) {
            int chn = tid + it * 256, m = chn >> 3, cl = (chn & 7) * 8;
            *(float4*)(ldsB + m * 64 + cl) = *(const float4*)(fW2t + m * 256 + k0 + cl);
        }
        __syncthreads();
#pragma unroll
        for (int ks = 0; ks < 2; ++ks) {
            const int kk = ks * 32 + q * 8;
            bh8 a = *(const bh8*)(f1buf + ln * 256 + k0 + kk);
#pragma unroll
            for (int nt = 0; nt < 4; ++nt) {
                bh8 b = *(const bh8*)(ldsB + (wid * 64 + nt * 16 + ln) * 64 + kk);
                acc2[nt] = __builtin_amdgcn_mfma_f32_16x16x32_bf16(a, b, acc2[nt], 0, 0, 0);
            }
        }
    }
#pragma unroll
    for (int nt = 0; nt < 4; ++nt)
#pragma unroll
        for (int r = 0; r < 4; ++r) {
            int row = q * 4 + r;
            int col = wid * 64 + nt * 16 + ln;
            f2buf[row * 256 + col] = gelu_(acc2[nt][r] + fb2[col]);
        }
    __syncthreads();

    // phase 3: nxt = clip(max(s, f2@fW3 + fb3), 0, 1); 4 rows per wave
#pragma unroll
    for (int rr = 0; rr < 4; ++rr) {
        int row = wid * 4 + rr;
        f32x4 v = *(const f32x4*)(f2buf + row * 256 + lane * 4);
        float p = v[0] * fW3[lane * 4 + 0] + v[1] * fW3[lane * 4 + 1]
                + v[2] * fW3[lane * 4 + 2] + v[3] * fW3[lane * 4 + 3];
        p += __shfl_xor(p, 1); p += __shfl_xor(p, 2); p += __shfl_xor(p, 4);
        p += __shfl_xor(p, 8); p += __shfl_xor(p, 16); p += __shfl_xor(p, 32);
        if (lane == 0) {
            int bg = row0 + row;
            float nxt = p + fb3[0];
            float sv = sp[bg];
            nxt = fminf(fmaxf(fmaxf(sv, nxt), 0.f), 1.f);
            sp[bg] = nxt;
            out[bg * 32 + t] = nxt;
        }
    }
}

// ---------------------------------------------------------------------------
extern "C" void kernel_launch(void* const* d_in, const int* in_sizes, int n_in,
                              void* d_out, int out_size, void* d_ws, size_t ws_size,
                              hipStream_t stream) {
    const float* ist   = (const float*)d_in[0];
    const float* lat   = (const float*)d_in[1];
    const float* vol   = (const float*)d_in[2];
    const float* thick = (const float*)d_in[3];
    const float* trap  = (const float*)d_in[4];
    const float* W_ih0 = (const float*)d_in[5];
    const float* W_hh0 = (const float*)d_in[6];
    const float* b0_   = (const float*)d_in[7];
    const float* W_ih1 = (const float*)d_in[8];
    const float* W_hh1 = (const float*)d_in[9];
    const float* b1_   = (const float*)d_in[10];
    const float* fW1   = (const float*)d_in[11];
    const float* fb1   = (const float*)d_in[12];
    const float* fW2   = (const float*)d_in[13];
    const float* fb2   = (const float*)d_in[14];
    const float* fW3   = (const float*)d_in[15];
    const float* fb3   = (const float*)d_in[16];
    const float* cW1   = (const float*)d_in[17];
    const float* cb1   = (const float*)d_in[18];
    const float* cW2   = (const float*)d_in[19];
    const float* cb2   = (const float*)d_in[20];

    char* ws = (char*)d_ws;
    u16*   Wp    = (u16*)(ws + WS_WP);
    u16*   fW1t  = (u16*)(ws + WS_FW1T);
    u16*   fW2t  = (u16*)(ws + WS_FW2T);
    float* fw1r0 = (float*)(ws + WS_FW1R0);
    float* w0col = (float*)(ws + WS_W0COL);
    float* Ee    = (float*)(ws + WS_EE);
    float* ratep = (float*)(ws + WS_RATE);
    float* sp    = (float*)(ws + WS_SP);
    u16*   h0    = (u16*)(ws + WS_H0);
    u16*   h1    = (u16*)(ws + WS_H1);
    u16*   c0    = (u16*)(ws + WS_C0);
    u16*   c1    = (u16*)(ws + WS_C1);
    float* out   = (float*)d_out;

    const bool big = ws_size >= (size_t)WS_EXT_END;
    u16* whh0b = (u16*)(ws + WS_WHH0B);
    u16* wih1b = (u16*)(ws + WS_WIH1B);
    u16* whh1b = (u16*)(ws + WS_WHH1B);

    k_setup<<<2048, 256, 0, stream>>>(ist, vol, thick, trap, W_ih0, fW1, fW2,
        h0, h1, c0, c1, Wp, w0col, fW1t, fW2t, fw1r0, Ee, ratep, sp, out + OFF_E);
    if (big)
        k_conv3<<<4096, 256, 0, stream>>>(W_hh0, W_ih1, W_hh1, whh0b, wih1b, whh1b);

    const void* pWhh0 = big ? (const void*)whh0b : (const void*)W_hh0;
    const void* pWih1 = big ? (const void*)wih1b : (const void*)W_ih1;
    const void* pWhh1 = big ? (const void*)whh1b : (const void*)W_hh1;
    const int wf = big ? 0 : 1;

    for (int t = 0; t < 32; ++t) {
        int cur = t & 1, nx = cur ^ 1;
        // lstm0: h0@W_hh0^T (K=512) + lat@Wp^T (K=256) + s*w0col + b0
        k_lstm_m<<<dim3(16, 16), 256, 0, stream>>>(
            h0 + cur * HS, 512, 8, pWhh0, 512, wf,
            lat, 1, 256, 4, Wp, 256, 0,
            w0col, sp, b0_, c0, h0 + nx * HS);
        // lstm1: h0n@W_ih1^T + h1@W_hh1^T + b1
        k_lstm_m<<<dim3(16, 16), 256, 0, stream>>>(
            h0 + nx * HS, 512, 8, pWih1, 512, wf,
            h1 + cur * HS, 0, 512, 8, pWhh1, 512, wf,
            (const float*)nullptr, (const float*)nullptr, b1_, c1, h1 + nx * HS);
        // fused pred + f-net + state update
        k_fnet<<<64, 256, 0, stream>>>(t, h1 + nx * HS, fW1t, fw1r0, fb1, fW2t, fb2,
            fW3, fb3, cW1, cb1, cW2, cb2, Ee, ratep, sp, out);
    }
}

// Round 8
// 2010.695 us; speedup vs baseline: 32.0111x; 1.5803x over previous
//
#include <hip/hip_runtime.h>
#include <hip/hip_bf16.h>

typedef unsigned short u16;
typedef unsigned int u32;
typedef __attribute__((ext_vector_type(8))) short bh8;     // 8 x bf16 MFMA A/B frag
typedef __attribute__((ext_vector_type(4))) float f32x4;   // MFMA C/D frag

#define KB_T 0.025851f
#define HS (1024 * 512)

// d_out (fp32): preds.T [1024][32] | E [1024] | gens.T [1024][32] | bps.T [1024][32]
#define OFF_E    32768
#define OFF_GENS 33792
#define OFF_BPS  66560

// ---- workspace layout (byte offsets); base total 7,754,752 B (proven safe)
#define WS_WP     0u         // [2048][256] bf16  (W_ih0[:,1:])
#define WS_FW1T   1048576u   // [256][512] bf16   (fW1[1:] ^T)
#define WS_FW2T   1310720u   // [256][256] bf16   (fW2 ^T)
#define WS_FW1R0  1441792u   // [256] f32         (fW1 row 0)
#define WS_W0COL  1442816u   // [2048] f32        (W_ih0[:,0])
#define WS_EE     1451008u   // [1024] f32
#define WS_RATE   1455104u   // [1024] f32
#define WS_SP     1459200u   // [1024] f32
#define WS_H0     1463296u   // 2x[1024][512] bf16 ping-pong
#define WS_H1     3560448u   // 2x[1024][512] bf16
#define WS_C0     5657600u   // [1024][512] bf16
#define WS_C1     6706176u   // [1024][512] bf16
#define WS_BASE_END 7754752u
// tier1 (ws >= 11949056): bf16 W_ih1 + W_hh1. tier2 (ws >= 14046208): + W_hh0
#define WS_WIH1B  7754752u
#define WS_WHH1B  9851904u
#define WS_T1_END 11949056u
#define WS_WHH0B  11949056u
#define WS_T2_END 14046208u

__device__ __forceinline__ float b2f(u16 u) { u32 x = ((u32)u) << 16; float f; __builtin_memcpy(&f, &x, 4); return f; }
__device__ __forceinline__ u16 f2b(float f) { __hip_bfloat16 h = __float2bfloat16(f); u16 u; __builtin_memcpy(&u, &h, 2); return u; }
__device__ __forceinline__ float sigf(float x) { return 1.f / (1.f + __expf(-x)); }
__device__ __forceinline__ float tanh_(float x) { return 1.f - 2.f / (__expf(2.f * x) + 1.f); }
__device__ __forceinline__ float gelu_(float x) { return 0.5f * x * (1.f + tanh_(0.7978845608f * (x + 0.044715f * x * x * x))); }

// stage 8 contiguous elements into LDS as bf16; src bf16 (16B copy) or fp32 (32B + cvt)
__device__ __forceinline__ void stage8(u16* dst, const void* src, int ofs, int srcf32) {
    if (srcf32) {
        const float* s = (const float*)src + ofs;
        float4 a = *(const float4*)s;
        float4 b = *(const float4*)(s + 4);
        u16 t[8] = {f2b(a.x), f2b(a.y), f2b(a.z), f2b(a.w),
                    f2b(b.x), f2b(b.y), f2b(b.z), f2b(b.w)};
        *(float4*)dst = *(const float4*)t;
    } else {
        *(float4*)dst = *(const float4*)((const u16*)src + ofs);
    }
}

// ---------------------------------------------------------------------------
// setup (proven R7): zero states; repack W_ih0 -> Wp+w0col; fW1 -> fW1t+fw1r0;
// fW2 -> fW2t; E/rate/s0. grid 2048 x 256.
// ---------------------------------------------------------------------------
__global__ __launch_bounds__(256) void k_setup(
    const float* __restrict__ ist, const float* __restrict__ vol, const float* __restrict__ thick,
    const float* __restrict__ trap, const float* __restrict__ W_ih0,
    const float* __restrict__ fW1, const float* __restrict__ fW2,
    u16* __restrict__ h0, u16* __restrict__ h1, u16* __restrict__ c0, u16* __restrict__ c1,
    u16* __restrict__ Wp, float* __restrict__ w0col,
    u16* __restrict__ fW1t, u16* __restrict__ fW2t, float* __restrict__ fw1r0,
    float* __restrict__ Ee, float* __restrict__ ratep, float* __restrict__ sp,
    float* __restrict__ outE)
{
    const int idx = blockIdx.x * 256 + threadIdx.x;
    h0[idx] = 0; h1[idx] = 0; c0[idx] = 0; c1[idx] = 0;
    Wp[idx] = f2b(W_ih0[(idx >> 8) * 257 + 1 + (idx & 255)]);
    if (idx < 131072) { int n = idx >> 9, k = idx & 511; fW1t[n * 512 + k] = f2b(fW1[(1 + k) * 256 + n]); }
    if (idx < 65536)  { int n = idx >> 8, k = idx & 255; fW2t[n * 256 + k] = f2b(fW2[k * 256 + n]); }
    if (idx < 2048)   w0col[idx] = W_ih0[idx * 257];
    if (idx < 256)    fw1r0[idx] = fW1[idx];
    if (idx < 1024) {
        float E = vol[idx] / thick[idx];
        float Ea = trap[idx * 8], ga = trap[idx * 8 + 1];
        ratep[idx] = __expf(-fmaxf(Ea - ga * E, 0.f) / KB_T);
        Ee[idx] = E;
        sp[idx] = ist[idx * 10 + 9];
        outE[idx] = E;
    }
}

// fp32 -> bf16 convert of one [2048][512] weight. grid 4096 x 256.
__global__ __launch_bounds__(256) void k_conv1(
    const float* __restrict__ a, u16* __restrict__ oa)
{
    const int idx = blockIdx.x * 256 + threadIdx.x;   // [0, 1048576)
    oa[idx] = f2b(a[idx]);
}

// ---------------------------------------------------------------------------
// MFMA LSTM cell v2. gates = bias + A1@W1^T + A2@W2^T [+ s*w0col].
// Tile 32 rows x 64 gate-cols (16 j); grid dim3(32, 32) = 1024 blocks (4/CU).
// LDS rows padded to 72 u16 (144B) -> b128 frag reads at the 8-cycle floor.
// gbuf (32x68 f32) overlays staging LDS (used only after final barrier).
// ---------------------------------------------------------------------------
__global__ __launch_bounds__(256) void k_lstm_m(
    const u16* __restrict__ A1, int lda1, int nk1, const void* __restrict__ W1, int ldw1, int w1f,
    const void* __restrict__ A2, int a2f, int lda2, int nk2, const void* __restrict__ W2, int ldw2, int w2f,
    const float* __restrict__ w0col, const float* __restrict__ s, const float* __restrict__ bias,
    u16* __restrict__ c, u16* __restrict__ hout)
{
    __shared__ __attribute__((aligned(16))) char smem[13824];
    u16*   ldsA = (u16*)smem;                // [32][72] u16, 4608 B
    u16*   ldsB = (u16*)(smem + 4608);       // [64][72] u16, 9216 B
    float* gbuf = (float*)smem;              // [32][68] f32, 8704 B (post-barrier overlay)

    const int tid = threadIdx.x, wid = tid >> 6, lane = tid & 63;
    const int q = lane >> 4, ln = lane & 15;
    const int wr = wid >> 1, wc = wid & 1;           // wave = 16 rows x 32 gate-cols
    const int j0 = blockIdx.x * 16, row0 = blockIdx.y * 32;

    f32x4 acc[2];
    acc[0] = f32x4{0.f, 0.f, 0.f, 0.f};
    acc[1] = f32x4{0.f, 0.f, 0.f, 0.f};

    for (int half = 0; half < 2; ++half) {
        const void* A = half ? A2 : (const void*)A1;
        const void* W = half ? W2 : W1;
        const int lda = half ? lda2 : lda1, ldw = half ? ldw2 : ldw1;
        const int nk = half ? nk2 : nk1;
        const int af = half ? a2f : 0;
        const int wf = half ? w2f : w1f;
        for (int kc = 0; kc < nk; ++kc) {
            const int k0 = kc * 64;
            __syncthreads();
            {   // ldsA: 32 rows x 64 k  (256 chunks, 1/thread)
                int r = tid >> 3, cl = (tid & 7) * 8;
                stage8(ldsA + r * 72 + cl, A, (row0 + r) * lda + k0 + cl, af);
            }
#pragma unroll
            for (int it = 0; it < 2; ++it) {  // ldsB: 64 gate-cols x 64 k (512 chunks)
                int chn = tid + it * 256, m = chn >> 3, cl = (chn & 7) * 8;
                int wrow = (m >> 4) * 512 + j0 + (m & 15);   // gate (m>>4), col j (m&15)
                stage8(ldsB + m * 72 + cl, W, wrow * ldw + k0 + cl, wf);
            }
            __syncthreads();
#pragma unroll
            for (int ks = 0; ks < 2; ++ks) {
                const int kk = ks * 32 + q * 8;
                bh8 afr = *(const bh8*)(ldsA + (wr * 16 + ln) * 72 + kk);
#pragma unroll
                for (int nt = 0; nt < 2; ++nt) {
                    bh8 bfr = *(const bh8*)(ldsB + (wc * 32 + nt * 16 + ln) * 72 + kk);
                    acc[nt] = __builtin_amdgcn_mfma_f32_16x16x32_bf16(afr, bfr, acc[nt], 0, 0, 0);
                }
            }
        }
    }
    __syncthreads();
    // C/D layout (measured m89/m91): col = lane&15, row = (lane>>4)*4 + reg
#pragma unroll
    for (int nt = 0; nt < 2; ++nt)
#pragma unroll
        for (int r = 0; r < 4; ++r) {
            int lrow = wr * 16 + q * 4 + r;
            int lcol = wc * 32 + nt * 16 + ln;
            gbuf[lrow * 68 + lcol] = acc[nt][r];
        }
    __syncthreads();
#pragma unroll
    for (int p = 0; p < 2; ++p) {
        int idx = p * 256 + tid;                 // 512 items: 32 rows x 16 j
        int bl = idx >> 4, j = idx & 15;
        int bg = row0 + bl, jg = j0 + j;
        float gi = gbuf[bl * 68 +  0 + j] + bias[jg];
        float gf = gbuf[bl * 68 + 16 + j] + bias[512 + jg];
        float gg = gbuf[bl * 68 + 32 + j] + bias[1024 + jg];
        float go = gbuf[bl * 68 + 48 + j] + bias[1536 + jg];
        if (w0col) {
            float sv = s[bg];
            gi += sv * w0col[jg];         gf += sv * w0col[512 + jg];
            gg += sv * w0col[1024 + jg];  go += sv * w0col[1536 + jg];
        }
        float cold = b2f(c[bg * 512 + jg]);
        float cn = sigf(gf) * cold + sigf(gi) * tanh_(gg);
        float hn = sigf(go) * tanh_(cn);
        c[bg * 512 + jg] = f2b(cn);
        hout[bg * 512 + jg] = f2b(hn);
    }
}

// ---------------------------------------------------------------------------
// Fused f-net (proven R7): pred/gen/bp + f1(MFMA) + f2(MFMA) + f3 + update.
// 16 rows/WG, 64 WGs, 256 threads.
// ---------------------------------------------------------------------------
__global__ __launch_bounds__(256) void k_fnet(
    int t,
    const u16* __restrict__ h1n, const u16* __restrict__ fW1t, const float* __restrict__ fw1r0,
    const float* __restrict__ fb1, const u16* __restrict__ fW2t, const float* __restrict__ fb2,
    const float* __restrict__ fW3, const float* __restrict__ fb3,
    const float* __restrict__ cW1, const float* __restrict__ cb1,
    const float* __restrict__ cW2, const float* __restrict__ cb2,
    const float* __restrict__ Ee, const float* __restrict__ ratep,
    float* __restrict__ sp, float* __restrict__ out)
{
    __shared__ __attribute__((aligned(16))) u16 ldsA[16 * 64];     // 2KB
    __shared__ __attribute__((aligned(16))) u16 ldsB[256 * 64];    // 32KB
    __shared__ __attribute__((aligned(16))) u16 f1buf[16 * 256];   // 8KB
    __shared__ __attribute__((aligned(16))) float f2buf[16 * 256]; // 16KB
    __shared__ float predb[16];

    const int tid = threadIdx.x, wid = tid >> 6, lane = tid & 63;
    const int q = lane >> 4, ln = lane & 15;
    const int row0 = blockIdx.x * 16;

    // phase 0: pred/gen/bp
#pragma unroll
    for (int pass = 0; pass < 2; ++pass) {
        int rl = wid * 4 + pass * 2 + (lane >> 5);
        int l = lane & 31;
        int bg = row0 + rl;
        float sv = sp[bg], Ev = Ee[bg];
        float z = sv * cW1[l] + Ev * cW1[32 + l] + cb1[l];
        float tv = tanh_(z) * cW2[l];
        tv += __shfl_xor(tv, 1); tv += __shfl_xor(tv, 2); tv += __shfl_xor(tv, 4);
        tv += __shfl_xor(tv, 8); tv += __shfl_xor(tv, 16);
        float gen = ratep[bg] * (1.f - sv);
        float pred = sv + gen + tv + cb2[0];
        if (l == 0) {
            predb[rl] = pred;
            out[OFF_GENS + bg * 32 + t] = gen;
            out[OFF_BPS + bg * 32 + t] = sigf(10.f * (pred - 0.5f));
        }
    }

    // phase 1: f1 = gelu(pred*fw1r0 + h1@fW1t^T + fb1), K=512
    f32x4 acc1[4];
#pragma unroll
    for (int b = 0; b < 4; b++) acc1[b] = f32x4{0.f, 0.f, 0.f, 0.f};
    for (int kc = 0; kc < 8; ++kc) {
        const int k0 = kc * 64;
        __syncthreads();
        if (tid < 128) {
            int r = tid >> 3, cl = (tid & 7) * 8;
            *(float4*)(ldsA + r * 64 + cl) = *(const float4*)(h1n + (row0 + r) * 512 + k0 + cl);
        }
#pragma unroll
        for (int it = 0; it < 8; ++it) {
            int chn = tid + it * 256, m = chn >> 3, cl = (chn & 7) * 8;
            *(float4*)(ldsB + m * 64 + cl) = *(const float4*)(fW1t + m * 512 + k0 + cl);
        }
        __syncthreads();
#pragma unroll
        for (int ks = 0; ks < 2; ++ks) {
            const int kk = ks * 32 + q * 8;
            bh8 a = *(const bh8*)(ldsA + ln * 64 + kk);
#pragma unroll
            for (int nt = 0; nt < 4; ++nt) {
                bh8 b = *(const bh8*)(ldsB + (wid * 64 + nt * 16 + ln) * 64 + kk);
                acc1[nt] = __builtin_amdgcn_mfma_f32_16x16x32_bf16(a, b, acc1[nt], 0, 0, 0);
            }
        }
    }
    __syncthreads();
#pragma unroll
    for (int nt = 0; nt < 4; ++nt)
#pragma unroll
        for (int r = 0; r < 4; ++r) {
            int row = q * 4 + r;
            int col = wid * 64 + nt * 16 + ln;
            float x = acc1[nt][r] + fb1[col] + predb[row] * fw1r0[col];
            f1buf[row * 256 + col] = f2b(gelu_(x));
        }

    // phase 2: f2 = gelu(f1@fW2t^T + fb2), K=256
    f32x4 acc2[4];
#pragma unroll
    for (int b = 0; b < 4; b++) acc2[b] = f32x4{0.f, 0.f, 0.f, 0.f};
    for (int kc = 0; kc < 4; ++kc) {
        const int k0 = kc * 64;
        __syncthreads();
#pragma unroll
        for (int it = 0; it < 8; ++it) {
            int chn = tid + it * 256, m = chn >> 3, cl = (chn & 7) * 8;
            *(float4*)(ldsB + m * 64 + cl) = *(const float4*)(fW2t + m * 256 + k0 + cl);
        }
        __syncthreads();
#pragma unroll
        for (int ks = 0; ks < 2; ++ks) {
            const int kk = ks * 32 + q * 8;
            bh8 a = *(const bh8*)(f1buf + ln * 256 + k0 + kk);
#pragma unroll
            for (int nt = 0; nt < 4; ++nt) {
                bh8 b = *(const bh8*)(ldsB + (wid * 64 + nt * 16 + ln) * 64 + kk);
                acc2[nt] = __builtin_amdgcn_mfma_f32_16x16x32_bf16(a, b, acc2[nt], 0, 0, 0);
            }
        }
    }
#pragma unroll
    for (int nt = 0; nt < 4; ++nt)
#pragma unroll
        for (int r = 0; r < 4; ++r) {
            int row = q * 4 + r;
            int col = wid * 64 + nt * 16 + ln;
            f2buf[row * 256 + col] = gelu_(acc2[nt][r] + fb2[col]);
        }
    __syncthreads();

    // phase 3: nxt = clip(max(s, f2@fW3 + fb3), 0, 1)
#pragma unroll
    for (int rr = 0; rr < 4; ++rr) {
        int row = wid * 4 + rr;
        f32x4 v = *(const f32x4*)(f2buf + row * 256 + lane * 4);
        float p = v[0] * fW3[lane * 4 + 0] + v[1] * fW3[lane * 4 + 1]
                + v[2] * fW3[lane * 4 + 2] + v[3] * fW3[lane * 4 + 3];
        p += __shfl_xor(p, 1); p += __shfl_xor(p, 2); p += __shfl_xor(p, 4);
        p += __shfl_xor(p, 8); p += __shfl_xor(p, 16); p += __shfl_xor(p, 32);
        if (lane == 0) {
            int bg = row0 + row;
            float nxt = p + fb3[0];
            float sv = sp[bg];
            nxt = fminf(fmaxf(fmaxf(sv, nxt), 0.f), 1.f);
            sp[bg] = nxt;
            out[bg * 32 + t] = nxt;
        }
    }
}

// ---------------------------------------------------------------------------
extern "C" void kernel_launch(void* const* d_in, const int* in_sizes, int n_in,
                              void* d_out, int out_size, void* d_ws, size_t ws_size,
                              hipStream_t stream) {
    const float* ist   = (const float*)d_in[0];
    const float* lat   = (const float*)d_in[1];
    const float* vol   = (const float*)d_in[2];
    const float* thick = (const float*)d_in[3];
    const float* trap  = (const float*)d_in[4];
    const float* W_ih0 = (const float*)d_in[5];
    const float* W_hh0 = (const float*)d_in[6];
    const float* b0_   = (const float*)d_in[7];
    const float* W_ih1 = (const float*)d_in[8];
    const float* W_hh1 = (const float*)d_in[9];
    const float* b1_   = (const float*)d_in[10];
    const float* fW1   = (const float*)d_in[11];
    const float* fb1   = (const float*)d_in[12];
    const float* fW2   = (const float*)d_in[13];
    const float* fb2   = (const float*)d_in[14];
    const float* fW3   = (const float*)d_in[15];
    const float* fb3   = (const float*)d_in[16];
    const float* cW1   = (const float*)d_in[17];
    const float* cb1   = (const float*)d_in[18];
    const float* cW2   = (const float*)d_in[19];
    const float* cb2   = (const float*)d_in[20];

    char* ws = (char*)d_ws;
    u16*   Wp    = (u16*)(ws + WS_WP);
    u16*   fW1t  = (u16*)(ws + WS_FW1T);
    u16*   fW2t  = (u16*)(ws + WS_FW2T);
    float* fw1r0 = (float*)(ws + WS_FW1R0);
    float* w0col = (float*)(ws + WS_W0COL);
    float* Ee    = (float*)(ws + WS_EE);
    float* ratep = (float*)(ws + WS_RATE);
    float* sp    = (float*)(ws + WS_SP);
    u16*   h0    = (u16*)(ws + WS_H0);
    u16*   h1    = (u16*)(ws + WS_H1);
    u16*   c0    = (u16*)(ws + WS_C0);
    u16*   c1    = (u16*)(ws + WS_C1);
    float* out   = (float*)d_out;

    const bool t1 = ws_size >= (size_t)WS_T1_END;   // bf16 W_ih1 + W_hh1
    const bool t2 = ws_size >= (size_t)WS_T2_END;   // + bf16 W_hh0
    u16* wih1b = (u16*)(ws + WS_WIH1B);
    u16* whh1b = (u16*)(ws + WS_WHH1B);
    u16* whh0b = (u16*)(ws + WS_WHH0B);

    k_setup<<<2048, 256, 0, stream>>>(ist, vol, thick, trap, W_ih0, fW1, fW2,
        h0, h1, c0, c1, Wp, w0col, fW1t, fW2t, fw1r0, Ee, ratep, sp, out + OFF_E);
    if (t1) {
        k_conv1<<<4096, 256, 0, stream>>>(W_ih1, wih1b);
        k_conv1<<<4096, 256, 0, stream>>>(W_hh1, whh1b);
    }
    if (t2) k_conv1<<<4096, 256, 0, stream>>>(W_hh0, whh0b);

    const void* pWhh0 = t2 ? (const void*)whh0b : (const void*)W_hh0;
    const void* pWih1 = t1 ? (const void*)wih1b : (const void*)W_ih1;
    const void* pWhh1 = t1 ? (const void*)whh1b : (const void*)W_hh1;
    const int wf0 = t2 ? 0 : 1;
    const int wf1 = t1 ? 0 : 1;

    for (int t = 0; t < 32; ++t) {
        int cur = t & 1, nx = cur ^ 1;
        // lstm0: h0@W_hh0^T (K=512) + lat@Wp^T (K=256) + s*w0col + b0
        k_lstm_m<<<dim3(32, 32), 256, 0, stream>>>(
            h0 + cur * HS, 512, 8, pWhh0, 512, wf0,
            lat, 1, 256, 4, Wp, 256, 0,
            w0col, sp, b0_, c0, h0 + nx * HS);
        // lstm1: h0n@W_ih1^T + h1@W_hh1^T + b1
        k_lstm_m<<<dim3(32, 32), 256, 0, stream>>>(
            h0 + nx * HS, 512, 8, pWih1, 512, wf1,
            h1 + cur * HS, 0, 512, 8, pWhh1, 512, wf1,
            (const float*)nullptr, (const float*)nullptr, b1_, c1, h1 + nx * HS);
        // fused pred + f-net + state update
        k_fnet<<<64, 256, 0, stream>>>(t, h1 + nx * HS, fW1t, fw1r0, fb1, fW2t, fb2,
            fW3, fb3, cW1, cb1, cW2, cb2, Ee, ratep, sp, out);
    }
}